// Round 4
// baseline (1497.429 us; speedup 1.0000x reference)
//
#include <hip/hip_runtime.h>
#include <math.h>

#define NS 150
#define LDW 152
#define NT 40
#define MS 200
#define MT 30
#define N_SWEEPS 6
#define ROUNDS (N_SWEEPS*(NT-1))
#define JITTER 0.1f
#define NTHR 512

// ---- workspace layout (floats) ----
#define WS_AW 0                 // Acol[j][32]   : 40*32  = 1280
#define WS_RV 1280              // ra[j][256]    : 40*256 = 10240
#define WS_QV 11520             // qa[j][256]    : 40*256 = 10240 -> 21760 total

// ---- LDS union layout (bytes) ----
#define OFF_MP    0        // 47392
#define OFF_PR    47392    // 8*152*4 = 4864 -> 52256
#define OFF_INVS  52256    // 32 -> 52288
#define OFF_DVS   52288    // 600 -> 52896 (pad)
#define OFF_SCS   52896    // 1800 -> 54704 (pad)
#define OFF_TSCS  54704    // 2400 -> 57104
#define OFF_GV    58704    // 600 -> 59304
#define OFF_WTJ   59424    // 4  -> 59428
#define SMEM_BYTES 59440
// jacobi-phase overlay (inside Mp region only):
#define OFF_A2    0        // 2*40*41*4 = 13120
#define OFF_VTS   13120    // 40*44*4 = 7040 -> 20160
#define OFF_PRM   20160    // 8*20*16 = 2560 -> 22720
#define OFF_TCS   22720    // 160 -> 22880   (< OFF_PR; gv/wtj live above)

// packed upper-tri storage: row r holds cols [r&~3, 152), 16B-aligned start.
__device__ __forceinline__ int rs_off(int r) {
    int g = r >> 2, rm = r & 3;
    return LDW * r - 8 * g * (g - 1) - 4 * rm * g;
}
__device__ constexpr int rs_off_c(int r) {
    return LDW * r - 8 * (r >> 2) * ((r >> 2) - 1) - 4 * (r & 3) * (r >> 2);
}

__device__ __forceinline__ void jac_params(const float (*A)[NT+1], float4* dst,
                                           int i, int rr) {
    int i0 = i, i1 = NT - 1 - i;
    int p = (i0 == 0) ? 0 : ((i0 - 1 + rr) % (NT - 1)) + 1;
    int q = ((i1 - 1 + rr) % (NT - 1)) + 1;
    if (p > q) { int tsw = p; p = q; q = tsw; }
    float app = A[p][p], aqq = A[q][q], apq = A[p][q];
    float c, s;
    if (apq == 0.0f) { c = 1.0f; s = 0.0f; }
    else {
        float tau = (aqq - app) / (2.0f * apq);
        float tt = ((tau >= 0.0f) ? 1.0f : -1.0f) / (fabsf(tau) + sqrtf(1.0f + tau*tau));
        c = rsqrtf(1.0f + tt*tt);
        s = tt * c;
    }
    dst[i] = make_float4(c, s, __int_as_float(p), __int_as_float(q));
}

#define ST4(K0) { \
    constexpr int b0_ = rs_off_c((K0)+0) - ((K0) & ~3); \
    constexpr int b1_ = rs_off_c((K0)+1) - ((K0) & ~3); \
    constexpr int b2_ = rs_off_c((K0)+2) - ((K0) & ~3); \
    constexpr int b3_ = rs_off_c((K0)+3) - ((K0) & ~3); \
    float uk0_ = u[(K0)+0] * Mp[b0_ + (K0)+0]; \
    qa += uk0_*uk0_;  ra += uk0_ * Mp[b0_ + 150]; \
    u[(K0)+1] -= Mp[b0_ + (K0)+1] * uk0_; \
    u[(K0)+2] -= Mp[b0_ + (K0)+2] * uk0_; \
    u[(K0)+3] -= Mp[b0_ + (K0)+3] * uk0_; \
    float uk1_ = u[(K0)+1] * Mp[b1_ + (K0)+1]; \
    qa += uk1_*uk1_;  ra += uk1_ * Mp[b1_ + 150]; \
    u[(K0)+2] -= Mp[b1_ + (K0)+2] * uk1_; \
    u[(K0)+3] -= Mp[b1_ + (K0)+3] * uk1_; \
    float uk2_ = u[(K0)+2] * Mp[b2_ + (K0)+2]; \
    qa += uk2_*uk2_;  ra += uk2_ * Mp[b2_ + 150]; \
    u[(K0)+3] -= Mp[b2_ + (K0)+3] * uk2_; \
    float uk3_ = u[(K0)+3] * Mp[b3_ + (K0)+3]; \
    qa += uk3_*uk3_;  ra += uk3_ * Mp[b3_ + 150]; \
    _Pragma("unroll") \
    for (int t_ = (K0)+4; t_ < NS; t_ += 4) { \
        float4 w0_ = *(const float4*)&Mp[b0_ + t_]; \
        float4 w1_ = *(const float4*)&Mp[b1_ + t_]; \
        float4 w2_ = *(const float4*)&Mp[b2_ + t_]; \
        float4 w3_ = *(const float4*)&Mp[b3_ + t_]; \
        u[t_+0] -= w0_.x*uk0_ + w1_.x*uk1_ + w2_.x*uk2_ + w3_.x*uk3_; \
        u[t_+1] -= w0_.y*uk0_ + w1_.y*uk1_ + w2_.y*uk2_ + w3_.y*uk3_; \
        u[t_+2] -= w0_.z*uk0_ + w1_.z*uk1_ + w2_.z*uk2_ + w3_.z*uk3_; \
        u[t_+3] -= w0_.w*uk0_ + w1_.w*uk1_ + w2_.w*uk2_ + w3_.w*uk3_; \
    } \
}

#define UI(K) { \
    float d0_ = tx - scs[(K)*3+0]; \
    float d1_ = ty - scs[(K)*3+1]; \
    float d2_ = tz - scs[(K)*3+2]; \
    u[(K)] = expf(-((d0_*d0_ + d1_*d1_)*ill2 + d2_*d2_*ile2)); }
#define UI10(K) UI((K)+0) UI((K)+1) UI((K)+2) UI((K)+3) UI((K)+4) \
                UI((K)+5) UI((K)+6) UI((K)+7) UI((K)+8) UI((K)+9)

// ABLATION build: the whole per-block pipeline as a template body; RJ/RB/RS
// repeat-counts re-run a phase from a deterministic re-init, so outputs are
// bit-identical and the extra dispatch time == that phase's cost.
template<int RJ, int RB, int RS>
__device__ __forceinline__ void gp_body(
        const float* __restrict__ sc,  const float* __restrict__ tc,
        const float* __restrict__ st,  const float* __restrict__ tsc,
        const float* __restrict__ ttc,
        const float* __restrict__ lll, const float* __restrict__ lle,
        const float* __restrict__ llt, const float* __restrict__ lnv,
        float* __restrict__ ws) {
    __shared__ __align__(16) char smem[SMEM_BYTES];
    int j = blockIdx.x, tid = threadIdx.x;

    auto A2   = (float (*)[NT][NT+1])(smem + OFF_A2);
    auto Vts  = (float (*)[44])(smem + OFF_VTS);
    auto prm  = (float4 (*)[NT/2])(smem + OFF_PRM);
    float* tcs  = (float*)(smem + OFF_TCS);
    float* gv   = (float*)(smem + OFF_GV);
    float* wtjs = (float*)(smem + OFF_WTJ);
    float* scs  = (float*)(smem + OFF_SCS);
    float* tscs = (float*)(smem + OFF_TSCS);

    float ilt2 = expf(-2.0f * llt[0]);
    if (tid < NT) tcs[tid] = tc[tid];
    for (int t = tid; t < NS*3; t += NTHR) scs[t] = sc[t];
    for (int t = tid; t < MS*3; t += NTHR) tscs[t] = tsc[t];
    __syncthreads();

    // ---------- phase J: Jacobi (repeatable: full re-init each rep) ----------
    for (int rj = 0; rj < RJ; ++rj) {
        for (int idx = tid; idx < NT*NT; idx += NTHR) {
            int i = idx / NT, jj = idx - i*NT;
            float dt = tcs[i] - tcs[jj];
            float v = expf(-dt*dt*ilt2);
            if (i == jj) v += JITTER;
            A2[0][i][jj] = v;
        }
        for (int idx = tid; idx < NT*44; idx += NTHR) {
            int jr = idx / 44, k = idx - jr*44;
            Vts[jr][k] = (jr == k) ? 1.0f : 0.0f;
        }
        __syncthreads();
        int wave = tid >> 6, lane = tid & 63;
        for (int rd = 0; rd < ROUNDS; ++rd) {
            int cur = rd & 1, nxt = cur ^ 1;
            float4* wp = prm[wave];
            if (lane < NT/2) jac_params(A2[cur], wp, lane, rd % (NT - 1));
            __builtin_amdgcn_wave_barrier();
            for (int t = tid; t < 600; t += NTHR) {
                if (t < 400) {
                    int bi = t / 20, bj = t - bi*20;
                    float4 Pi = wp[bi], Pj = wp[bj];
                    int pi = __float_as_int(Pi.z), qi = __float_as_int(Pi.w);
                    int pj = __float_as_int(Pj.z), qj = __float_as_int(Pj.w);
                    float ci = Pi.x, si = Pi.y, cj = Pj.x, sj = Pj.y;
                    float a00 = A2[cur][pi][pj], a01 = A2[cur][pi][qj];
                    float a10 = A2[cur][qi][pj], a11 = A2[cur][qi][qj];
                    float b00 = ci*a00 - si*a10, b01 = ci*a01 - si*a11;
                    float b10 = si*a00 + ci*a10, b11 = si*a01 + ci*a11;
                    A2[nxt][pi][pj] = cj*b00 - sj*b01; A2[nxt][pi][qj] = sj*b00 + cj*b01;
                    A2[nxt][qi][pj] = cj*b10 - sj*b11; A2[nxt][qi][qj] = sj*b10 + cj*b11;
                } else {
                    int u2 = t - 400;
                    int pr = u2 / 10, ch = (u2 - pr*10) << 2;
                    float4 P = wp[pr];
                    int pj = __float_as_int(P.z), qj = __float_as_int(P.w);
                    float c = P.x, s = P.y;
                    float4 vp = *(float4*)&Vts[pj][ch];
                    float4 vq = *(float4*)&Vts[qj][ch];
                    float4 np, nq;
                    np.x = c*vp.x - s*vq.x; nq.x = s*vp.x + c*vq.x;
                    np.y = c*vp.y - s*vq.y; nq.y = s*vp.y + c*vq.y;
                    np.z = c*vp.z - s*vq.z; nq.z = s*vp.z + c*vq.z;
                    np.w = c*vp.w - s*vq.w; nq.w = s*vp.w + c*vq.w;
                    *(float4*)&Vts[pj][ch] = np;
                    *(float4*)&Vts[qj][ch] = nq;
                }
            }
            __syncthreads();
        }
    }
    const int fin = ROUNDS & 1;
    if (tid == 0) wtjs[0] = A2[fin][j][j];
    for (int s = tid; s < NS; s += NTHR) {
        const float4* va = (const float4*)&Vts[j][0];
        const float4* sa = (const float4*)&st[s*NT];
        float acc = 0.0f;
        #pragma unroll
        for (int c4 = 0; c4 < NT/4; ++c4) {
            float4 a = va[c4], b = sa[c4];
            acc += a.x*b.x + a.y*b.y + a.z*b.z + a.w*b.w;
        }
        gv[s] = acc;
    }
    if (tid < MT) {
        float ttv = ttc[tid];
        float acc = 0.0f;
        for (int t = 0; t < NT; ++t) {
            float dt = ttv - tcs[t];
            acc += expf(-dt*dt*ilt2) * Vts[j][t];
        }
        ws[WS_AW + j*32 + tid] = acc;
    }
    __syncthreads();

    // ---------- phase B: build + factor + scale (repeatable: full rebuild) ----------
    float* Mp   = (float*)(smem + OFF_MP);
    auto   Pr   = (float (*)[LDW])(smem + OFF_PR);
    float* invs = (float*)(smem + OFF_INVS);
    float* dvs  = (float*)(smem + OFF_DVS);
    float wtj = wtjs[0];
    float nv = expf(lnv[0]);
    float ill2 = expf(-2.0f * lll[0]);
    float ile2 = expf(-2.0f * lle[0]);
    for (int rb = 0; rb < RB; ++rb) {
        for (int idx = tid; idx < NS*LDW; idx += NTHR) {
            int r = idx / LDW, c = idx - r*LDW;
            int rbase = r & ~3;
            if (c < rbase) continue;
            float v;
            if (c < NS) {
                float d0 = scs[r*3+0] - scs[c*3+0];
                float d1 = scs[r*3+1] - scs[c*3+1];
                float d2 = scs[r*3+2] - scs[c*3+2];
                v = wtj * expf(-((d0*d0 + d1*d1)*ill2 + d2*d2*ile2));
                if (c == r) v += wtj * JITTER + nv;
            } else if (c == NS) {
                v = gv[r];
            } else {
                v = 0.0f;
            }
            Mp[rs_off(r) + c - rbase] = v;
        }
        __syncthreads();
        for (int k0 = 0; k0 < NS - 1; k0 += 8) {
            int P = NS - k0; if (P > 8) P = 8;
            int W4 = (LDW - k0) >> 2;
            if (tid < W4) {
                int off[8];
                #pragma unroll
                for (int i = 0; i < 8; ++i)
                    off[i] = (i < P) ? (rs_off(k0 + i) - ((i >= 4) ? 4 : 0)) : 0;
                float Bm[8][8];
                #pragma unroll
                for (int i = 0; i < 8; ++i) {
                    #pragma unroll
                    for (int c = 0; c < 8; ++c)
                        Bm[i][c] = (i < P && c >= i) ? Mp[off[i] + c]
                                                     : ((c == i) ? 1.0f : 0.0f);
                }
                float Lf[8][8]; float iv[8];
                #pragma unroll
                for (int k = 0; k < 8; ++k) {
                    iv[k] = 1.0f / Bm[k][k];
                    #pragma unroll
                    for (int i = k + 1; i < 8; ++i) {
                        float l = Bm[k][i] * iv[k];
                        Lf[i][k] = l;
                        #pragma unroll
                        for (int c = i; c < 8; ++c) Bm[i][c] -= l * Bm[k][c];
                    }
                }
                if (tid == 0) {
                    #pragma unroll
                    for (int i = 0; i < 8; ++i) invs[i] = iv[i];
                }
                int C = tid << 2;
                float4 m[8];
                #pragma unroll
                for (int i = 0; i < 8; ++i) {
                    bool ok = (i < P) && (i < 4 || C >= 4);
                    m[i] = ok ? *(float4*)&Mp[off[i] + C] : make_float4(0,0,0,0);
                }
                #pragma unroll
                for (int i = 1; i < 8; ++i) {
                    #pragma unroll
                    for (int k = 0; k < i; ++k) {
                        float l = Lf[i][k];
                        m[i].x -= l*m[k].x; m[i].y -= l*m[k].y;
                        m[i].z -= l*m[k].z; m[i].w -= l*m[k].w;
                    }
                }
                #pragma unroll
                for (int i = 0; i < 8; ++i) *(float4*)&Pr[i][C] = m[i];
            }
            __syncthreads();
            for (int r = k0 + 1 + tid; r < NS; r += NTHR) {
                int rc = r - k0;
                float f[8];
                #pragma unroll
                for (int i = 0; i < 8; ++i)
                    f[i] = (rc > i && i < P) ? Pr[i][rc] * invs[i] : 0.0f;
                int rbase = r & ~3;
                int ro = rs_off(r) - rbase;
                for (int C = rbase; C < LDW; C += 4) {
                    int pc = C - k0;
                    float4 v = *(float4*)&Mp[ro + C];
                    #pragma unroll
                    for (int i = 0; i < 8; ++i) {
                        float4 p = *(float4*)&Pr[i][pc];
                        v.x -= f[i]*p.x; v.y -= f[i]*p.y;
                        v.z -= f[i]*p.z; v.w -= f[i]*p.w;
                    }
                    *(float4*)&Mp[ro + C] = v;
                }
            }
            __syncthreads();
        }
        for (int r = tid; r < NS; r += NTHR)
            dvs[r] = rsqrtf(Mp[rs_off(r) + r - (r & ~3)]);
        __syncthreads();
        for (int idx = tid; idx < NS*LDW; idx += NTHR) {
            int r = idx / LDW, c = idx - r*LDW;
            int rbase = r & ~3;
            if (c < rbase) continue;
            int t = rs_off(r) + c - rbase;
            float dvr = dvs[r];
            if (c == r) Mp[t] = dvr;
            else if (c > r) Mp[t] *= dvr;
        }
        __syncthreads();
    }

    // ---------- phase S: trsm (repeatable: pure function of Mp) ----------
    for (int rs2 = 0; rs2 < RS; ++rs2) {
        if (tid < MS) {
            float tx = tscs[tid*3+0], ty = tscs[tid*3+1], tz = tscs[tid*3+2];
            float u[152];
            UI10(0)  UI10(10) UI10(20) UI10(30) UI10(40)
            UI10(50) UI10(60) UI10(70) UI10(80) UI10(90)
            UI10(100) UI10(110) UI10(120) UI10(130) UI10(140)
            u[150] = 0.0f; u[151] = 0.0f;
            float qa = 0.0f, ra = 0.0f;
            ST4(0)   ST4(4)   ST4(8)   ST4(12)  ST4(16)  ST4(20)  ST4(24)
            ST4(28)  ST4(32)  ST4(36)  ST4(40)  ST4(44)  ST4(48)  ST4(52)
            ST4(56)  ST4(60)  ST4(64)  ST4(68)  ST4(72)  ST4(76)  ST4(80)
            ST4(84)  ST4(88)  ST4(92)  ST4(96)  ST4(100) ST4(104) ST4(108)
            ST4(112) ST4(116) ST4(120) ST4(124) ST4(128) ST4(132) ST4(136)
            ST4(140) ST4(144)
            {
                constexpr int b8_ = rs_off_c(148) - 148;
                constexpr int b9_ = rs_off_c(149) - 148;
                float uk8_ = u[148] * Mp[b8_ + 148];
                qa += uk8_*uk8_;  ra += uk8_ * Mp[b8_ + 150];
                u[149] -= Mp[b8_ + 149] * uk8_;
                float uk9_ = u[149] * Mp[b9_ + 149];
                qa += uk9_*uk9_;  ra += uk9_ * Mp[b9_ + 150];
            }
            ws[WS_RV + j*256 + tid] = ra;
            ws[WS_QV + j*256 + tid] = qa;
        }
    }
}

// Three ablation kernels: one doubled phase each. Distinct names for rocprof.
__global__ void __launch_bounds__(NTHR, 2) gp_ablJ(
        const float* __restrict__ sc,  const float* __restrict__ tc,
        const float* __restrict__ st,  const float* __restrict__ tsc,
        const float* __restrict__ ttc,
        const float* __restrict__ lll, const float* __restrict__ lle,
        const float* __restrict__ llt, const float* __restrict__ lnv,
        float* __restrict__ ws) {
    gp_body<2,1,1>(sc, tc, st, tsc, ttc, lll, lle, llt, lnv, ws);
}
__global__ void __launch_bounds__(NTHR, 2) gp_ablB(
        const float* __restrict__ sc,  const float* __restrict__ tc,
        const float* __restrict__ st,  const float* __restrict__ tsc,
        const float* __restrict__ ttc,
        const float* __restrict__ lll, const float* __restrict__ lle,
        const float* __restrict__ llt, const float* __restrict__ lnv,
        float* __restrict__ ws) {
    gp_body<1,2,1>(sc, tc, st, tsc, ttc, lll, lle, llt, lnv, ws);
}
__global__ void __launch_bounds__(NTHR, 2) gp_ablS(
        const float* __restrict__ sc,  const float* __restrict__ tc,
        const float* __restrict__ st,  const float* __restrict__ tsc,
        const float* __restrict__ ttc,
        const float* __restrict__ lll, const float* __restrict__ lle,
        const float* __restrict__ llt, const float* __restrict__ lnv,
        float* __restrict__ ws) {
    gp_body<1,1,2>(sc, tc, st, tsc, ttc, lll, lle, llt, lnv, ws);
}

// ---------- reduction kernel: out = rank-40 combine of workspace partials ----------
__global__ void __launch_bounds__(256) gp_reduce(
        const float* __restrict__ ws, const float* __restrict__ lsv,
        float* __restrict__ out) {
    int idx = blockIdx.x * 256 + threadIdx.x;
    if (idx >= MS*MT) return;
    int is = idx / MT, it = idx - is*MT;
    float p = 0.0f, q = 0.0f;
    #pragma unroll
    for (int jj = 0; jj < NT; ++jj) {
        float a = ws[WS_AW + jj*32 + it];
        p += a * ws[WS_RV + jj*256 + is];
        q += a * a * ws[WS_QV + jj*256 + is];
    }
    out[idx] = p;
    out[MS*MT + idx] = expf(lsv[0]) - q;
}

extern "C" void kernel_launch(void* const* d_in, const int* in_sizes, int n_in,
                              void* d_out, int out_size, void* d_ws, size_t ws_size,
                              hipStream_t stream) {
    const float* sc  = (const float*)d_in[0];   // 150x3
    const float* tc  = (const float*)d_in[1];   // 40x1
    const float* st  = (const float*)d_in[2];   // 150x40
    const float* tsc = (const float*)d_in[3];   // 200x3
    const float* ttc = (const float*)d_in[4];   // 30x1
    const float* lll = (const float*)d_in[5];
    const float* lle = (const float*)d_in[6];
    const float* llt = (const float*)d_in[7];
    const float* lnv = (const float*)d_in[8];
    const float* lsv = (const float*)d_in[9];
    float* out = (float*)d_out;
    float* ws  = (float*)d_ws;

    // Ablation: three identical-output dispatches, each doubling one phase.
    // Per-dispatch dur in rocprof = T_base + T_phase; all write identical ws.
    hipLaunchKernelGGL(gp_ablJ, dim3(NT), dim3(NTHR), 0, stream,
                       sc, tc, st, tsc, ttc, lll, lle, llt, lnv, ws);
    hipLaunchKernelGGL(gp_ablB, dim3(NT), dim3(NTHR), 0, stream,
                       sc, tc, st, tsc, ttc, lll, lle, llt, lnv, ws);
    hipLaunchKernelGGL(gp_ablS, dim3(NT), dim3(NTHR), 0, stream,
                       sc, tc, st, tsc, ttc, lll, lle, llt, lnv, ws);
    hipLaunchKernelGGL(gp_reduce, dim3((MS*MT + 255)/256), dim3(256), 0, stream,
                       ws, lsv, out);
}

// Round 6
// 620.941 us; speedup vs baseline: 2.4115x; 2.4115x over previous
//
#include <hip/hip_runtime.h>
#include <math.h>

#define NS 150
#define LDW 152
#define NT 40
#define MS 200
#define MT 30
#define N_SWEEPS 6
#define ROUNDS (N_SWEEPS*(NT-1))
#define JITTER 0.1f
#define NTHR 704   // 11 waves: Jacobi A-items waves 0-6, V-items waves 7-10

// ---- workspace layout (floats) ----
#define WS_AW 0                 // Acol[j][32]   : 40*32  = 1280
#define WS_RV 1280              // ra[j][256]    : 40*256 = 10240
#define WS_QV 11520             // qa[j][256]    : 40*256 = 10240 -> 21760 total

// ---- LDS union layout (bytes) ----
#define OFF_MP    0        // 47392
#define OFF_PR    47392    // 8*152*4 = 4864 -> 52256
#define OFF_INVS  52256    // 32 -> 52288
#define OFF_DVS   52288    // 600 -> 52896 (pad)
#define OFF_SCS   52896    // 1800 -> 54704 (pad)
#define OFF_TSCS  54704    // 2400 -> 57104
#define OFF_GV    58704    // 600 -> 59304
#define OFF_WTJ   59424    // 4  -> 59428
#define SMEM_BYTES 59440
// jacobi-phase overlay (inside Mp region only):
#define OFF_A2    0        // 2*40*41*4 = 13120
#define OFF_VTS   13120    // 40*44*4 = 7040 -> 20160
#define OFF_TCS   20160    // 160 -> 20320   (< OFF_PR; gv/wtj live above)

// packed upper-tri storage: row r holds cols [r&~3, 152), 16B-aligned start.
__device__ __forceinline__ int rs_off(int r) {
    int g = r >> 2, rm = r & 3;
    return LDW * r - 8 * g * (g - 1) - 4 * rm * g;
}
__device__ constexpr int rs_off_c(int r) {
    return LDW * r - 8 * (r >> 2) * ((r >> 2) - 1) - 4 * (r & 3) * (r >> 2);
}

#define ST4(K0) { \
    constexpr int b0_ = rs_off_c((K0)+0) - ((K0) & ~3); \
    constexpr int b1_ = rs_off_c((K0)+1) - ((K0) & ~3); \
    constexpr int b2_ = rs_off_c((K0)+2) - ((K0) & ~3); \
    constexpr int b3_ = rs_off_c((K0)+3) - ((K0) & ~3); \
    float uk0_ = u[(K0)+0] * Mp[b0_ + (K0)+0]; \
    qa += uk0_*uk0_;  ra += uk0_ * Mp[b0_ + 150]; \
    u[(K0)+1] -= Mp[b0_ + (K0)+1] * uk0_; \
    u[(K0)+2] -= Mp[b0_ + (K0)+2] * uk0_; \
    u[(K0)+3] -= Mp[b0_ + (K0)+3] * uk0_; \
    float uk1_ = u[(K0)+1] * Mp[b1_ + (K0)+1]; \
    qa += uk1_*uk1_;  ra += uk1_ * Mp[b1_ + 150]; \
    u[(K0)+2] -= Mp[b1_ + (K0)+2] * uk1_; \
    u[(K0)+3] -= Mp[b1_ + (K0)+3] * uk1_; \
    float uk2_ = u[(K0)+2] * Mp[b2_ + (K0)+2]; \
    qa += uk2_*uk2_;  ra += uk2_ * Mp[b2_ + 150]; \
    u[(K0)+3] -= Mp[b2_ + (K0)+3] * uk2_; \
    float uk3_ = u[(K0)+3] * Mp[b3_ + (K0)+3]; \
    qa += uk3_*uk3_;  ra += uk3_ * Mp[b3_ + 150]; \
    _Pragma("unroll") \
    for (int t_ = (K0)+4; t_ < NS; t_ += 4) { \
        float4 w0_ = *(const float4*)&Mp[b0_ + t_]; \
        float4 w1_ = *(const float4*)&Mp[b1_ + t_]; \
        float4 w2_ = *(const float4*)&Mp[b2_ + t_]; \
        float4 w3_ = *(const float4*)&Mp[b3_ + t_]; \
        u[t_+0] -= w0_.x*uk0_ + w1_.x*uk1_ + w2_.x*uk2_ + w3_.x*uk3_; \
        u[t_+1] -= w0_.y*uk0_ + w1_.y*uk1_ + w2_.y*uk2_ + w3_.y*uk3_; \
        u[t_+2] -= w0_.z*uk0_ + w1_.z*uk1_ + w2_.z*uk2_ + w3_.z*uk3_; \
        u[t_+3] -= w0_.w*uk0_ + w1_.w*uk1_ + w2_.w*uk2_ + w3_.w*uk3_; \
    } \
}

#define UI(K) { \
    float d0_ = tx - scs[(K)*3+0]; \
    float d1_ = ty - scs[(K)*3+1]; \
    float d2_ = tz - scs[(K)*3+2]; \
    u[(K)] = expf(-((d0_*d0_ + d1_*d1_)*ill2 + d2_*d2_*ile2)); }
#define UI10(K) UI((K)+0) UI((K)+1) UI((K)+2) UI((K)+3) UI((K)+4) \
                UI((K)+5) UI((K)+6) UI((K)+7) UI((K)+8) UI((K)+9)

// ONE main kernel, 40 blocks x 704 threads.
// Jacobi (ablation: 184us of 344) restructured: params in registers +
// __shfl broadcast, no prm LDS round-trip, no straggler double-duty.
// R5 NaN post-mortem: __shfl is ds_bpermute under EXEC — a pull from a lane
// that is INACTIVE at the shfl point returns invalid data. R5 put the shfls
// inside `if (tid<400)`; wave 6 (tids 384..447) had source lanes 16..19
// inactive there -> zero params -> Jacobi corrupted -> non-SPD Mp ->
// rsqrtf(neg) = NaN. Fix: branch at WAVE granularity (tid>>6 is wave-uniform,
// all 64 lanes enter together), do the shfls with all lanes active using
// clamped dummy indices, and mask only the WRITES by tid.
__global__ void __launch_bounds__(NTHR, 2) gp_block(
        const float* __restrict__ sc,  const float* __restrict__ tc,
        const float* __restrict__ st,  const float* __restrict__ tsc,
        const float* __restrict__ ttc,
        const float* __restrict__ lll, const float* __restrict__ lle,
        const float* __restrict__ llt, const float* __restrict__ lnv,
        float* __restrict__ ws) {
    __shared__ __align__(16) char smem[SMEM_BYTES];
    int j = blockIdx.x, tid = threadIdx.x;

    auto A2   = (float (*)[NT][NT+1])(smem + OFF_A2);
    auto Vts  = (float (*)[44])(smem + OFF_VTS);
    float* tcs  = (float*)(smem + OFF_TCS);
    float* gv   = (float*)(smem + OFF_GV);
    float* wtjs = (float*)(smem + OFF_WTJ);
    float* scs  = (float*)(smem + OFF_SCS);
    float* tscs = (float*)(smem + OFF_TSCS);

    float ilt2 = expf(-2.0f * llt[0]);
    if (tid < NT) tcs[tid] = tc[tid];
    for (int t = tid; t < NS*3; t += NTHR) scs[t] = sc[t];
    for (int t = tid; t < MS*3; t += NTHR) tscs[t] = tsc[t];
    __syncthreads();
    for (int idx = tid; idx < NT*NT; idx += NTHR) {
        int i = idx / NT, jj = idx - i*NT;
        float dt = tcs[i] - tcs[jj];
        float v = expf(-dt*dt*ilt2);
        if (i == jj) v += JITTER;
        A2[0][i][jj] = v;
    }
    for (int idx = tid; idx < NT*44; idx += NTHR) {
        int jr = idx / 44, k = idx - jr*44;
        Vts[jr][k] = (jr == k) ? 1.0f : 0.0f;
    }
    __syncthreads();

    int lane = tid & 63;
    int wv = tid >> 6;   // wave index: uniform across the wave
    for (int rd = 0; rd < ROUNDS; ++rd) {
        int cur = rd & 1, nxt = cur ^ 1;
        int rr = rd % (NT - 1);
        // ---- params in registers (all lanes compute; lanes>=20 mirror lane 0
        //      so their A2 reads broadcast; only lanes 0..19 are shfl sources)
        float pcv, psv; int ppv, pqv;
        {
            int i0 = (lane < NT/2) ? lane : 0;
            int p = (i0 == 0) ? 0 : ((i0 - 1 + rr) % (NT - 1)) + 1;
            int i1 = NT - 1 - i0;
            int q = ((i1 - 1 + rr) % (NT - 1)) + 1;
            if (p > q) { int tsw = p; p = q; q = tsw; }
            float app = A2[cur][p][p], aqq = A2[cur][q][q], apq = A2[cur][p][q];
            float c, s;
            if (apq == 0.0f) { c = 1.0f; s = 0.0f; }
            else {
                float tau = (aqq - app) / (2.0f * apq);
                float tt = ((tau >= 0.0f) ? 1.0f : -1.0f)
                           / (fabsf(tau) + sqrtf(1.0f + tau*tau));
                c = rsqrtf(1.0f + tt*tt);
                s = tt * c;
            }
            pcv = c; psv = s; ppv = p; pqv = q;
        }
        if (wv <= 6) {
            // A-path: waves 0..6 (items tid<400). Shfls with ALL lanes active;
            // dummy item 0 for tid>=400, write masked below.
            int ta = (tid < 400) ? tid : 0;
            int bi = ta / 20, bj = ta - bi*20;
            float ci = __shfl(pcv, bi), si = __shfl(psv, bi);
            int   pi = __shfl(ppv, bi), qi = __shfl(pqv, bi);
            float cj = __shfl(pcv, bj), sj = __shfl(psv, bj);
            int   pj = __shfl(ppv, bj), qj = __shfl(pqv, bj);
            if (tid < 400) {
                float a00 = A2[cur][pi][pj], a01 = A2[cur][pi][qj];
                float a10 = A2[cur][qi][pj], a11 = A2[cur][qi][qj];
                float b00 = ci*a00 - si*a10, b01 = ci*a01 - si*a11;
                float b10 = si*a00 + ci*a10, b11 = si*a01 + ci*a11;
                A2[nxt][pi][pj] = cj*b00 - sj*b01; A2[nxt][pi][qj] = sj*b00 + cj*b01;
                A2[nxt][qi][pj] = cj*b10 - sj*b11; A2[nxt][qi][qj] = sj*b10 + cj*b11;
            }
        } else {
            // V-path: waves 7..10 (items tid in [448,648)). Same discipline.
            int tvv = (tid >= 448 && tid < 648) ? (tid - 448) : 0;
            int pr = tvv / 10, ch = (tvv - pr*10) << 2;
            float c = __shfl(pcv, pr), s = __shfl(psv, pr);
            int  pj = __shfl(ppv, pr), qj = __shfl(pqv, pr);
            if (tid < 648) {
                float4 vp = *(float4*)&Vts[pj][ch];
                float4 vq = *(float4*)&Vts[qj][ch];
                float4 np, nq;
                np.x = c*vp.x - s*vq.x; nq.x = s*vp.x + c*vq.x;
                np.y = c*vp.y - s*vq.y; nq.y = s*vp.y + c*vq.y;
                np.z = c*vp.z - s*vq.z; nq.z = s*vp.z + c*vq.z;
                np.w = c*vp.w - s*vq.w; nq.w = s*vp.w + c*vq.w;
                *(float4*)&Vts[pj][ch] = np;
                *(float4*)&Vts[qj][ch] = nq;
            }
        }
        __syncthreads();
    }
    const int fin = ROUNDS & 1;
    if (tid == 0) wtjs[0] = A2[fin][j][j];
    for (int s = tid; s < NS; s += NTHR) {
        const float4* va = (const float4*)&Vts[j][0];
        const float4* sa = (const float4*)&st[s*NT];
        float acc = 0.0f;
        #pragma unroll
        for (int c4 = 0; c4 < NT/4; ++c4) {
            float4 a = va[c4], b = sa[c4];
            acc += a.x*b.x + a.y*b.y + a.z*b.z + a.w*b.w;
        }
        gv[s] = acc;
    }
    if (tid < MT) {
        float ttv = ttc[tid];
        float acc = 0.0f;
        for (int t = 0; t < NT; ++t) {
            float dt = ttv - tcs[t];
            acc += expf(-dt*dt*ilt2) * Vts[j][t];
        }
        ws[WS_AW + j*32 + tid] = acc;
    }
    __syncthreads();

    // ---------- phase 2: build + rank-8 factor + scale + trsm ----------
    float* Mp   = (float*)(smem + OFF_MP);
    auto   Pr   = (float (*)[LDW])(smem + OFF_PR);
    float* invs = (float*)(smem + OFF_INVS);
    float* dvs  = (float*)(smem + OFF_DVS);
    float wtj = wtjs[0];
    float nv = expf(lnv[0]);
    float ill2 = expf(-2.0f * lll[0]);
    float ile2 = expf(-2.0f * lle[0]);
    for (int idx = tid; idx < NS*LDW; idx += NTHR) {
        int r = idx / LDW, c = idx - r*LDW;
        int rbase = r & ~3;
        if (c < rbase) continue;
        float v;
        if (c < NS) {
            float d0 = scs[r*3+0] - scs[c*3+0];
            float d1 = scs[r*3+1] - scs[c*3+1];
            float d2 = scs[r*3+2] - scs[c*3+2];
            v = wtj * expf(-((d0*d0 + d1*d1)*ill2 + d2*d2*ile2));
            if (c == r) v += wtj * JITTER + nv;   // spatial jitter rides wtj
        } else if (c == NS) {
            v = gv[r];
        } else {
            v = 0.0f;
        }
        Mp[rs_off(r) + c - rbase] = v;
    }
    __syncthreads();
    for (int k0 = 0; k0 < NS - 1; k0 += 8) {
        int P = NS - k0; if (P > 8) P = 8;
        int W4 = (LDW - k0) >> 2;
        // phase A (single wave): redundant 8x8 elimination + chunk pre-elim -> Pr
        if (tid < W4) {
            int off[8];
            #pragma unroll
            for (int i = 0; i < 8; ++i)
                off[i] = (i < P) ? (rs_off(k0 + i) - ((i >= 4) ? 4 : 0)) : 0;
            float Bm[8][8];
            #pragma unroll
            for (int i = 0; i < 8; ++i) {
                #pragma unroll
                for (int c = 0; c < 8; ++c)
                    Bm[i][c] = (i < P && c >= i) ? Mp[off[i] + c]
                                                 : ((c == i) ? 1.0f : 0.0f);
            }
            float Lf[8][8]; float iv[8];
            #pragma unroll
            for (int k = 0; k < 8; ++k) {
                iv[k] = 1.0f / Bm[k][k];
                #pragma unroll
                for (int i = k + 1; i < 8; ++i) {
                    float l = Bm[k][i] * iv[k];
                    Lf[i][k] = l;
                    #pragma unroll
                    for (int c = i; c < 8; ++c) Bm[i][c] -= l * Bm[k][c];
                }
            }
            if (tid == 0) {
                #pragma unroll
                for (int i = 0; i < 8; ++i) invs[i] = iv[i];
            }
            int C = tid << 2;
            float4 m[8];
            #pragma unroll
            for (int i = 0; i < 8; ++i) {
                bool ok = (i < P) && (i < 4 || C >= 4);
                m[i] = ok ? *(float4*)&Mp[off[i] + C] : make_float4(0,0,0,0);
            }
            #pragma unroll
            for (int i = 1; i < 8; ++i) {
                #pragma unroll
                for (int k = 0; k < i; ++k) {
                    float l = Lf[i][k];
                    m[i].x -= l*m[k].x; m[i].y -= l*m[k].y;
                    m[i].z -= l*m[k].z; m[i].w -= l*m[k].w;
                }
            }
            #pragma unroll
            for (int i = 0; i < 8; ++i) *(float4*)&Pr[i][C] = m[i];
        }
        __syncthreads();
        // phase B: rank-8 trailing update, thread-per-row, contiguous f4 sweep
        for (int r = k0 + 1 + tid; r < NS; r += NTHR) {
            int rc = r - k0;
            float f[8];
            #pragma unroll
            for (int i = 0; i < 8; ++i)
                f[i] = (rc > i && i < P) ? Pr[i][rc] * invs[i] : 0.0f;
            int rbase = r & ~3;
            int ro = rs_off(r) - rbase;
            for (int C = rbase; C < LDW; C += 4) {
                int pc = C - k0;
                float4 v = *(float4*)&Mp[ro + C];
                #pragma unroll
                for (int i = 0; i < 8; ++i) {
                    float4 p = *(float4*)&Pr[i][pc];
                    v.x -= f[i]*p.x; v.y -= f[i]*p.y;
                    v.z -= f[i]*p.z; v.w -= f[i]*p.w;
                }
                *(float4*)&Mp[ro + C] = v;
            }
        }
        __syncthreads();
    }
    // scale in place: diag slot = 1/d, cols>r (incl. RHS col 150 -> y) *= 1/d
    for (int r = tid; r < NS; r += NTHR)
        dvs[r] = rsqrtf(Mp[rs_off(r) + r - (r & ~3)]);
    __syncthreads();
    for (int idx = tid; idx < NS*LDW; idx += NTHR) {
        int r = idx / LDW, c = idx - r*LDW;
        int rbase = r & ~3;
        if (c < rbase) continue;
        int t = rs_off(r) + c - rbase;
        float dvr = dvs[r];
        if (c == r) Mp[t] = dvr;
        else if (c > r) Mp[t] *= dvr;
    }
    __syncthreads();
    // fused trsm: thread-per-test-column, u[] fully static -> register-resident
    if (tid < MS) {
        float tx = tscs[tid*3+0], ty = tscs[tid*3+1], tz = tscs[tid*3+2];
        float u[152];
        UI10(0)  UI10(10) UI10(20) UI10(30) UI10(40)
        UI10(50) UI10(60) UI10(70) UI10(80) UI10(90)
        UI10(100) UI10(110) UI10(120) UI10(130) UI10(140)
        u[150] = 0.0f; u[151] = 0.0f;
        float qa = 0.0f, ra = 0.0f;
        ST4(0)   ST4(4)   ST4(8)   ST4(12)  ST4(16)  ST4(20)  ST4(24)
        ST4(28)  ST4(32)  ST4(36)  ST4(40)  ST4(44)  ST4(48)  ST4(52)
        ST4(56)  ST4(60)  ST4(64)  ST4(68)  ST4(72)  ST4(76)  ST4(80)
        ST4(84)  ST4(88)  ST4(92)  ST4(96)  ST4(100) ST4(104) ST4(108)
        ST4(112) ST4(116) ST4(120) ST4(124) ST4(128) ST4(132) ST4(136)
        ST4(140) ST4(144)
        {   // tail: k = 148, 149
            constexpr int b8_ = rs_off_c(148) - 148;
            constexpr int b9_ = rs_off_c(149) - 148;
            float uk8_ = u[148] * Mp[b8_ + 148];
            qa += uk8_*uk8_;  ra += uk8_ * Mp[b8_ + 150];
            u[149] -= Mp[b8_ + 149] * uk8_;
            float uk9_ = u[149] * Mp[b9_ + 149];
            qa += uk9_*uk9_;  ra += uk9_ * Mp[b9_ + 150];
        }
        ws[WS_RV + j*256 + tid] = ra;
        ws[WS_QV + j*256 + tid] = qa;
    }
}

// ---------- reduction kernel: out = rank-40 combine of workspace partials ----------
__global__ void __launch_bounds__(256) gp_reduce(
        const float* __restrict__ ws, const float* __restrict__ lsv,
        float* __restrict__ out) {
    int idx = blockIdx.x * 256 + threadIdx.x;
    if (idx >= MS*MT) return;
    int is = idx / MT, it = idx - is*MT;
    float p = 0.0f, q = 0.0f;
    #pragma unroll
    for (int jj = 0; jj < NT; ++jj) {
        float a = ws[WS_AW + jj*32 + it];
        p += a * ws[WS_RV + jj*256 + is];
        q += a * a * ws[WS_QV + jj*256 + is];
    }
    out[idx] = p;
    out[MS*MT + idx] = expf(lsv[0]) - q;
}

extern "C" void kernel_launch(void* const* d_in, const int* in_sizes, int n_in,
                              void* d_out, int out_size, void* d_ws, size_t ws_size,
                              hipStream_t stream) {
    const float* sc  = (const float*)d_in[0];   // 150x3
    const float* tc  = (const float*)d_in[1];   // 40x1
    const float* st  = (const float*)d_in[2];   // 150x40
    const float* tsc = (const float*)d_in[3];   // 200x3
    const float* ttc = (const float*)d_in[4];   // 30x1
    const float* lll = (const float*)d_in[5];
    const float* lle = (const float*)d_in[6];
    const float* llt = (const float*)d_in[7];
    const float* lnv = (const float*)d_in[8];
    const float* lsv = (const float*)d_in[9];
    float* out = (float*)d_out;
    float* ws  = (float*)d_ws;

    hipLaunchKernelGGL(gp_block, dim3(NT), dim3(NTHR), 0, stream,
                       sc, tc, st, tsc, ttc, lll, lle, llt, lnv, ws);
    hipLaunchKernelGGL(gp_reduce, dim3((MS*MT + 255)/256), dim3(256), 0, stream,
                       ws, lsv, out);
}

// Round 7
// 445.991 us; speedup vs baseline: 3.3575x; 1.3923x over previous
//
#include <hip/hip_runtime.h>
#include <math.h>

#define NS 150
#define LDW 152
#define NT 40
#define MS 200
#define MT 30
#define N_SWEEPS 6
#define ROUNDS (N_SWEEPS*(NT-1))
#define JITTER 0.1f
#define NTHR 512   // 8 waves: PROVEN register regime (VGPR 128 + AGPR headroom).
                   // R6's 704-thread block made the compiler cap VGPRs at 84
                   // (2-blocks/CU heuristic, 6 waves/SIMD) -> real scratch
                   // spills -> 6 MB HBM traffic, +220us. Do not raise NTHR.

// ---- workspace layout (floats) ----
#define WS_AW 0                 // Acol[j][32]   : 40*32  = 1280
#define WS_RV 1280              // ra[j][256]    : 40*256 = 10240
#define WS_QV 11520             // qa[j][256]    : 40*256 = 10240 -> 21760 total

// ---- LDS union layout (bytes) ----
#define OFF_MP    0        // 47392
#define OFF_PR    47392    // 8*152*4 = 4864 -> 52256
#define OFF_INVS  52256    // 32 -> 52288
#define OFF_DVS   52288    // 600 -> 52896 (pad)
#define OFF_SCS   52896    // 1800 -> 54704 (pad)
#define OFF_TSCS  54704    // 2400 -> 57104
#define OFF_GV    58704    // 600 -> 59304
#define OFF_WTJ   59424    // 4  -> 59428
#define SMEM_BYTES 59440
// jacobi-phase overlay (inside Mp region only):
#define OFF_A2    0        // 2*40*41*4 = 13120
#define OFF_VTS   13120    // 40*44*4 = 7040 -> 20160
#define OFF_TCS   20160    // 160 -> 20320   (< OFF_PR; gv/wtj live above)

// packed upper-tri storage: row r holds cols [r&~3, 152), 16B-aligned start.
__device__ __forceinline__ int rs_off(int r) {
    int g = r >> 2, rm = r & 3;
    return LDW * r - 8 * g * (g - 1) - 4 * rm * g;
}
__device__ constexpr int rs_off_c(int r) {
    return LDW * r - 8 * (r >> 2) * ((r >> 2) - 1) - 4 * (r & 3) * (r >> 2);
}

#define ST4(K0) { \
    constexpr int b0_ = rs_off_c((K0)+0) - ((K0) & ~3); \
    constexpr int b1_ = rs_off_c((K0)+1) - ((K0) & ~3); \
    constexpr int b2_ = rs_off_c((K0)+2) - ((K0) & ~3); \
    constexpr int b3_ = rs_off_c((K0)+3) - ((K0) & ~3); \
    float uk0_ = u[(K0)+0] * Mp[b0_ + (K0)+0]; \
    qa += uk0_*uk0_;  ra += uk0_ * Mp[b0_ + 150]; \
    u[(K0)+1] -= Mp[b0_ + (K0)+1] * uk0_; \
    u[(K0)+2] -= Mp[b0_ + (K0)+2] * uk0_; \
    u[(K0)+3] -= Mp[b0_ + (K0)+3] * uk0_; \
    float uk1_ = u[(K0)+1] * Mp[b1_ + (K0)+1]; \
    qa += uk1_*uk1_;  ra += uk1_ * Mp[b1_ + 150]; \
    u[(K0)+2] -= Mp[b1_ + (K0)+2] * uk1_; \
    u[(K0)+3] -= Mp[b1_ + (K0)+3] * uk1_; \
    float uk2_ = u[(K0)+2] * Mp[b2_ + (K0)+2]; \
    qa += uk2_*uk2_;  ra += uk2_ * Mp[b2_ + 150]; \
    u[(K0)+3] -= Mp[b2_ + (K0)+3] * uk2_; \
    float uk3_ = u[(K0)+3] * Mp[b3_ + (K0)+3]; \
    qa += uk3_*uk3_;  ra += uk3_ * Mp[b3_ + 150]; \
    _Pragma("unroll") \
    for (int t_ = (K0)+4; t_ < NS; t_ += 4) { \
        float4 w0_ = *(const float4*)&Mp[b0_ + t_]; \
        float4 w1_ = *(const float4*)&Mp[b1_ + t_]; \
        float4 w2_ = *(const float4*)&Mp[b2_ + t_]; \
        float4 w3_ = *(const float4*)&Mp[b3_ + t_]; \
        u[t_+0] -= w0_.x*uk0_ + w1_.x*uk1_ + w2_.x*uk2_ + w3_.x*uk3_; \
        u[t_+1] -= w0_.y*uk0_ + w1_.y*uk1_ + w2_.y*uk2_ + w3_.y*uk3_; \
        u[t_+2] -= w0_.z*uk0_ + w1_.z*uk1_ + w2_.z*uk2_ + w3_.z*uk3_; \
        u[t_+3] -= w0_.w*uk0_ + w1_.w*uk1_ + w2_.w*uk2_ + w3_.w*uk3_; \
    } \
}

#define UI(K) { \
    float d0_ = tx - scs[(K)*3+0]; \
    float d1_ = ty - scs[(K)*3+1]; \
    float d2_ = tz - scs[(K)*3+2]; \
    u[(K)] = expf(-((d0_*d0_ + d1_*d1_)*ill2 + d2_*d2_*ile2)); }
#define UI10(K) UI((K)+0) UI((K)+1) UI((K)+2) UI((K)+3) UI((K)+4) \
                UI((K)+5) UI((K)+6) UI((K)+7) UI((K)+8) UI((K)+9)

// ONE main kernel, 40 blocks x 512 threads.
// Jacobi: params in registers + __shfl broadcast (no prm LDS round-trip).
// Work split, single-duty: A-items (400, float scalars) on tid<400;
// V-items widened to float8 (100 items) on tid in [400,500). All 12 shfls
// execute UNCONDITIONALLY with full exec mask and clamped dummy source
// indices (lanes 0..19 are always-active sources) BEFORE any branch —
// the R5 inactive-source-lane hazard is structurally excluded. Only the
// writes are tid-masked. Element math identical to R3 -> bit-identical out.
__global__ void __launch_bounds__(NTHR, 2) gp_block(
        const float* __restrict__ sc,  const float* __restrict__ tc,
        const float* __restrict__ st,  const float* __restrict__ tsc,
        const float* __restrict__ ttc,
        const float* __restrict__ lll, const float* __restrict__ lle,
        const float* __restrict__ llt, const float* __restrict__ lnv,
        float* __restrict__ ws) {
    __shared__ __align__(16) char smem[SMEM_BYTES];
    int j = blockIdx.x, tid = threadIdx.x;

    auto A2   = (float (*)[NT][NT+1])(smem + OFF_A2);
    auto Vts  = (float (*)[44])(smem + OFF_VTS);
    float* tcs  = (float*)(smem + OFF_TCS);
    float* gv   = (float*)(smem + OFF_GV);
    float* wtjs = (float*)(smem + OFF_WTJ);
    float* scs  = (float*)(smem + OFF_SCS);
    float* tscs = (float*)(smem + OFF_TSCS);

    float ilt2 = expf(-2.0f * llt[0]);
    if (tid < NT) tcs[tid] = tc[tid];
    for (int t = tid; t < NS*3; t += NTHR) scs[t] = sc[t];
    for (int t = tid; t < MS*3; t += NTHR) tscs[t] = tsc[t];
    __syncthreads();
    for (int idx = tid; idx < NT*NT; idx += NTHR) {
        int i = idx / NT, jj = idx - i*NT;
        float dt = tcs[i] - tcs[jj];
        float v = expf(-dt*dt*ilt2);
        if (i == jj) v += JITTER;
        A2[0][i][jj] = v;
    }
    for (int idx = tid; idx < NT*44; idx += NTHR) {
        int jr = idx / 44, k = idx - jr*44;
        Vts[jr][k] = (jr == k) ? 1.0f : 0.0f;
    }
    __syncthreads();

    int lane = tid & 63;
    // static item assignment (round-invariant)
    const int ta = (tid < 400) ? tid : 0;            // A-item index
    const int bi = ta / 20, bj = ta - bi*20;
    const int tv = (tid >= 400 && tid < 500) ? (tid - 400) : 0;  // V-item
    const int pr = tv / 5, ch = (tv - pr*5) << 3;    // pair, col*8
    for (int rd = 0; rd < ROUNDS; ++rd) {
        int cur = rd & 1, nxt = cur ^ 1;
        int rr = rd % (NT - 1);
        // ---- params in registers (all lanes compute; lanes>=20 mirror lane 0
        //      so their A2 reads broadcast; only lanes 0..19 are shfl sources)
        float pcv, psv; int ppv, pqv;
        {
            int i0 = (lane < NT/2) ? lane : 0;
            int p = (i0 == 0) ? 0 : ((i0 - 1 + rr) % (NT - 1)) + 1;
            int i1 = NT - 1 - i0;
            int q = ((i1 - 1 + rr) % (NT - 1)) + 1;
            if (p > q) { int tsw = p; p = q; q = tsw; }
            float app = A2[cur][p][p], aqq = A2[cur][q][q], apq = A2[cur][p][q];
            float c, s;
            if (apq == 0.0f) { c = 1.0f; s = 0.0f; }
            else {
                float tau = (aqq - app) / (2.0f * apq);
                float tt = ((tau >= 0.0f) ? 1.0f : -1.0f)
                           / (fabsf(tau) + sqrtf(1.0f + tau*tau));
                c = rsqrtf(1.0f + tt*tt);
                s = tt * c;
            }
            pcv = c; psv = s; ppv = p; pqv = q;
        }
        // ---- uniform shfl block: full exec mask, sources 0..19 always active
        float ci = __shfl(pcv, bi), si = __shfl(psv, bi);
        int   pi = __shfl(ppv, bi), qi = __shfl(pqv, bi);
        float cj = __shfl(pcv, bj), sj = __shfl(psv, bj);
        int   pj = __shfl(ppv, bj), qj = __shfl(pqv, bj);
        float cv = __shfl(pcv, pr), sv = __shfl(psv, pr);
        int   pv = __shfl(ppv, pr), qv = __shfl(pqv, pr);
        // ---- masked work (no shfls below this line)
        if (tid < 400) {
            float a00 = A2[cur][pi][pj], a01 = A2[cur][pi][qj];
            float a10 = A2[cur][qi][pj], a11 = A2[cur][qi][qj];
            float b00 = ci*a00 - si*a10, b01 = ci*a01 - si*a11;
            float b10 = si*a00 + ci*a10, b11 = si*a01 + ci*a11;
            A2[nxt][pi][pj] = cj*b00 - sj*b01; A2[nxt][pi][qj] = sj*b00 + cj*b01;
            A2[nxt][qi][pj] = cj*b10 - sj*b11; A2[nxt][qi][qj] = sj*b10 + cj*b11;
        } else if (tid < 500) {
            float4 vp0 = *(float4*)&Vts[pv][ch];
            float4 vp1 = *(float4*)&Vts[pv][ch+4];
            float4 vq0 = *(float4*)&Vts[qv][ch];
            float4 vq1 = *(float4*)&Vts[qv][ch+4];
            float4 np0, np1, nq0, nq1;
            np0.x = cv*vp0.x - sv*vq0.x; nq0.x = sv*vp0.x + cv*vq0.x;
            np0.y = cv*vp0.y - sv*vq0.y; nq0.y = sv*vp0.y + cv*vq0.y;
            np0.z = cv*vp0.z - sv*vq0.z; nq0.z = sv*vp0.z + cv*vq0.z;
            np0.w = cv*vp0.w - sv*vq0.w; nq0.w = sv*vp0.w + cv*vq0.w;
            np1.x = cv*vp1.x - sv*vq1.x; nq1.x = sv*vp1.x + cv*vq1.x;
            np1.y = cv*vp1.y - sv*vq1.y; nq1.y = sv*vp1.y + cv*vq1.y;
            np1.z = cv*vp1.z - sv*vq1.z; nq1.z = sv*vp1.z + cv*vq1.z;
            np1.w = cv*vp1.w - sv*vq1.w; nq1.w = sv*vp1.w + cv*vq1.w;
            *(float4*)&Vts[pv][ch]   = np0;
            *(float4*)&Vts[pv][ch+4] = np1;
            *(float4*)&Vts[qv][ch]   = nq0;
            *(float4*)&Vts[qv][ch+4] = nq1;
        }
        __syncthreads();
    }
    const int fin = ROUNDS & 1;
    if (tid == 0) wtjs[0] = A2[fin][j][j];
    for (int s = tid; s < NS; s += NTHR) {
        const float4* va = (const float4*)&Vts[j][0];
        const float4* sa = (const float4*)&st[s*NT];
        float acc = 0.0f;
        #pragma unroll
        for (int c4 = 0; c4 < NT/4; ++c4) {
            float4 a = va[c4], b = sa[c4];
            acc += a.x*b.x + a.y*b.y + a.z*b.z + a.w*b.w;
        }
        gv[s] = acc;
    }
    if (tid < MT) {
        float ttv = ttc[tid];
        float acc = 0.0f;
        for (int t = 0; t < NT; ++t) {
            float dt = ttv - tcs[t];
            acc += expf(-dt*dt*ilt2) * Vts[j][t];
        }
        ws[WS_AW + j*32 + tid] = acc;
    }
    __syncthreads();

    // ---------- phase 2: build + rank-8 factor + scale + trsm ----------
    float* Mp   = (float*)(smem + OFF_MP);
    auto   Pr   = (float (*)[LDW])(smem + OFF_PR);
    float* invs = (float*)(smem + OFF_INVS);
    float* dvs  = (float*)(smem + OFF_DVS);
    float wtj = wtjs[0];
    float nv = expf(lnv[0]);
    float ill2 = expf(-2.0f * lll[0]);
    float ile2 = expf(-2.0f * lle[0]);
    for (int idx = tid; idx < NS*LDW; idx += NTHR) {
        int r = idx / LDW, c = idx - r*LDW;
        int rbase = r & ~3;
        if (c < rbase) continue;
        float v;
        if (c < NS) {
            float d0 = scs[r*3+0] - scs[c*3+0];
            float d1 = scs[r*3+1] - scs[c*3+1];
            float d2 = scs[r*3+2] - scs[c*3+2];
            v = wtj * expf(-((d0*d0 + d1*d1)*ill2 + d2*d2*ile2));
            if (c == r) v += wtj * JITTER + nv;   // spatial jitter rides wtj
        } else if (c == NS) {
            v = gv[r];
        } else {
            v = 0.0f;
        }
        Mp[rs_off(r) + c - rbase] = v;
    }
    __syncthreads();
    for (int k0 = 0; k0 < NS - 1; k0 += 8) {
        int P = NS - k0; if (P > 8) P = 8;
        int W4 = (LDW - k0) >> 2;
        // phase A (single wave): redundant 8x8 elimination + chunk pre-elim -> Pr
        if (tid < W4) {
            int off[8];
            #pragma unroll
            for (int i = 0; i < 8; ++i)
                off[i] = (i < P) ? (rs_off(k0 + i) - ((i >= 4) ? 4 : 0)) : 0;
            float Bm[8][8];
            #pragma unroll
            for (int i = 0; i < 8; ++i) {
                #pragma unroll
                for (int c = 0; c < 8; ++c)
                    Bm[i][c] = (i < P && c >= i) ? Mp[off[i] + c]
                                                 : ((c == i) ? 1.0f : 0.0f);
            }
            float Lf[8][8]; float iv[8];
            #pragma unroll
            for (int k = 0; k < 8; ++k) {
                iv[k] = 1.0f / Bm[k][k];
                #pragma unroll
                for (int i = k + 1; i < 8; ++i) {
                    float l = Bm[k][i] * iv[k];
                    Lf[i][k] = l;
                    #pragma unroll
                    for (int c = i; c < 8; ++c) Bm[i][c] -= l * Bm[k][c];
                }
            }
            if (tid == 0) {
                #pragma unroll
                for (int i = 0; i < 8; ++i) invs[i] = iv[i];
            }
            int C = tid << 2;
            float4 m[8];
            #pragma unroll
            for (int i = 0; i < 8; ++i) {
                bool ok = (i < P) && (i < 4 || C >= 4);
                m[i] = ok ? *(float4*)&Mp[off[i] + C] : make_float4(0,0,0,0);
            }
            #pragma unroll
            for (int i = 1; i < 8; ++i) {
                #pragma unroll
                for (int k = 0; k < i; ++k) {
                    float l = Lf[i][k];
                    m[i].x -= l*m[k].x; m[i].y -= l*m[k].y;
                    m[i].z -= l*m[k].z; m[i].w -= l*m[k].w;
                }
            }
            #pragma unroll
            for (int i = 0; i < 8; ++i) *(float4*)&Pr[i][C] = m[i];
        }
        __syncthreads();
        // phase B: rank-8 trailing update, thread-per-row, contiguous f4 sweep
        for (int r = k0 + 1 + tid; r < NS; r += NTHR) {
            int rc = r - k0;
            float f[8];
            #pragma unroll
            for (int i = 0; i < 8; ++i)
                f[i] = (rc > i && i < P) ? Pr[i][rc] * invs[i] : 0.0f;
            int rbase = r & ~3;
            int ro = rs_off(r) - rbase;
            for (int C = rbase; C < LDW; C += 4) {
                int pc = C - k0;
                float4 v = *(float4*)&Mp[ro + C];
                #pragma unroll
                for (int i = 0; i < 8; ++i) {
                    float4 p = *(float4*)&Pr[i][pc];
                    v.x -= f[i]*p.x; v.y -= f[i]*p.y;
                    v.z -= f[i]*p.z; v.w -= f[i]*p.w;
                }
                *(float4*)&Mp[ro + C] = v;
            }
        }
        __syncthreads();
    }
    // scale in place: diag slot = 1/d, cols>r (incl. RHS col 150 -> y) *= 1/d
    for (int r = tid; r < NS; r += NTHR)
        dvs[r] = rsqrtf(Mp[rs_off(r) + r - (r & ~3)]);
    __syncthreads();
    for (int idx = tid; idx < NS*LDW; idx += NTHR) {
        int r = idx / LDW, c = idx - r*LDW;
        int rbase = r & ~3;
        if (c < rbase) continue;
        int t = rs_off(r) + c - rbase;
        float dvr = dvs[r];
        if (c == r) Mp[t] = dvr;
        else if (c > r) Mp[t] *= dvr;
    }
    __syncthreads();
    // fused trsm: thread-per-test-column, u[] fully static -> register/AGPR
    if (tid < MS) {
        float tx = tscs[tid*3+0], ty = tscs[tid*3+1], tz = tscs[tid*3+2];
        float u[152];
        UI10(0)  UI10(10) UI10(20) UI10(30) UI10(40)
        UI10(50) UI10(60) UI10(70) UI10(80) UI10(90)
        UI10(100) UI10(110) UI10(120) UI10(130) UI10(140)
        u[150] = 0.0f; u[151] = 0.0f;
        float qa = 0.0f, ra = 0.0f;
        ST4(0)   ST4(4)   ST4(8)   ST4(12)  ST4(16)  ST4(20)  ST4(24)
        ST4(28)  ST4(32)  ST4(36)  ST4(40)  ST4(44)  ST4(48)  ST4(52)
        ST4(56)  ST4(60)  ST4(64)  ST4(68)  ST4(72)  ST4(76)  ST4(80)
        ST4(84)  ST4(88)  ST4(92)  ST4(96)  ST4(100) ST4(104) ST4(108)
        ST4(112) ST4(116) ST4(120) ST4(124) ST4(128) ST4(132) ST4(136)
        ST4(140) ST4(144)
        {   // tail: k = 148, 149
            constexpr int b8_ = rs_off_c(148) - 148;
            constexpr int b9_ = rs_off_c(149) - 148;
            float uk8_ = u[148] * Mp[b8_ + 148];
            qa += uk8_*uk8_;  ra += uk8_ * Mp[b8_ + 150];
            u[149] -= Mp[b8_ + 149] * uk8_;
            float uk9_ = u[149] * Mp[b9_ + 149];
            qa += uk9_*uk9_;  ra += uk9_ * Mp[b9_ + 150];
        }
        ws[WS_RV + j*256 + tid] = ra;
        ws[WS_QV + j*256 + tid] = qa;
    }
}

// ---------- reduction kernel: out = rank-40 combine of workspace partials ----------
__global__ void __launch_bounds__(256) gp_reduce(
        const float* __restrict__ ws, const float* __restrict__ lsv,
        float* __restrict__ out) {
    int idx = blockIdx.x * 256 + threadIdx.x;
    if (idx >= MS*MT) return;
    int is = idx / MT, it = idx - is*MT;
    float p = 0.0f, q = 0.0f;
    #pragma unroll
    for (int jj = 0; jj < NT; ++jj) {
        float a = ws[WS_AW + jj*32 + it];
        p += a * ws[WS_RV + jj*256 + is];
        q += a * a * ws[WS_QV + jj*256 + is];
    }
    out[idx] = p;
    out[MS*MT + idx] = expf(lsv[0]) - q;
}

extern "C" void kernel_launch(void* const* d_in, const int* in_sizes, int n_in,
                              void* d_out, int out_size, void* d_ws, size_t ws_size,
                              hipStream_t stream) {
    const float* sc  = (const float*)d_in[0];   // 150x3
    const float* tc  = (const float*)d_in[1];   // 40x1
    const float* st  = (const float*)d_in[2];   // 150x40
    const float* tsc = (const float*)d_in[3];   // 200x3
    const float* ttc = (const float*)d_in[4];   // 30x1
    const float* lll = (const float*)d_in[5];
    const float* lle = (const float*)d_in[6];
    const float* llt = (const float*)d_in[7];
    const float* lnv = (const float*)d_in[8];
    const float* lsv = (const float*)d_in[9];
    float* out = (float*)d_out;
    float* ws  = (float*)d_ws;

    hipLaunchKernelGGL(gp_block, dim3(NT), dim3(NTHR), 0, stream,
                       sc, tc, st, tsc, ttc, lll, lle, llt, lnv, ws);
    hipLaunchKernelGGL(gp_reduce, dim3((MS*MT + 255)/256), dim3(256), 0, stream,
                       ws, lsv, out);
}